// Round 2
// baseline (313.710 us; speedup 1.0000x reference)
//
#include <hip/hip_runtime.h>
#include <math.h>

#define NN 8192        // n_nodes
#define NE 262144      // edges per adjacency list
#define TOTAL (2*NE)   // 524288
#define CAP 128        // bucket capacity per row (mean 64, sd 8; max ~95)
#define CSTR 16        // cnt stride in ints: ONE counter per 64B line (atomic line-contention fix)
#define HALF 4096      // columns per half-row tile (16 KB LDS -> full occupancy)

typedef float f4 __attribute__((ext_vector_type(4)));

struct Pair { int c; float v; };

// Workspace layout (bytes):
//   [0, 512K)               cnt[8192*16] padded row cursors (only [r*16] used)
//   [512K, 512K+4)          ovf_cnt
//   [1M, 1M+8MB)            bucket Pair[8192][128]
//   [1M+8MB, +128KB)        ovf int4[8192]  (r, c, bits(w*v), 0)
#define CNT_BYTES ((size_t)NN * CSTR * 4)          // 524288
#define BK_OFF ((size_t)1 << 20)                   // 1 MB
#define OV_OFF (BK_OFF + (size_t)NN * CAP * sizeof(Pair))

// Single-pass bucket build: blend weight applied at scatter time.
// i<NE handles list s, else list t — branch is block-uniform (256 | NE).
__global__ __launch_bounds__(256) void fill_kernel(
        const int* __restrict__ rows_s, const int* __restrict__ cols_s,
        const float* __restrict__ vals_s,
        const int* __restrict__ rows_t, const int* __restrict__ cols_t,
        const float* __restrict__ vals_t,
        const float* __restrict__ gamma,
        int* __restrict__ cnt, Pair* __restrict__ bucket,
        int* __restrict__ ovf_cnt, int4* __restrict__ ovf) {
    int i = blockIdx.x * blockDim.x + threadIdx.x;
    float alpha = 1.0f / (1.0f + expf(-gamma[0]));
    int r, c; float v, w;
    if (i < NE) { r = rows_s[i]; c = cols_s[i]; v = vals_s[i]; w = alpha; }
    else { int j = i - NE; r = rows_t[j]; c = cols_t[j]; v = vals_t[j]; w = 1.0f - alpha; }
    float wv = w * v;
    // One counter per 64B line: removes 16-counters/line serialization at the
    // device-scope atomic coherence point (1024 -> 64 RMWs per line).
    int pos = atomicAdd(&cnt[r * CSTR], 1);
    if (pos < CAP) {
        Pair p; p.c = c; p.v = wv;
        bucket[r * CAP + pos] = p;
    } else {
        // Statistically unreachable at these sizes; kept for correctness.
        int k = atomicAdd(ovf_cnt, 1);
        int4 e; e.x = r; e.y = c; e.z = __float_as_int(wv); e.w = 0;
        ovf[k] = e;
    }
}

// One block per half-row (16 KB LDS): 8 blocks/CU = 32 waves/CU (full occupancy,
// vs 5 blocks/20 waves with whole-row 32 KB tiles). Both halves scan the full
// bucket row (traffic is trivial) so each computes the complete row sum locally.
__global__ __launch_bounds__(256) void row_kernel(
        const int* __restrict__ cnt, const Pair* __restrict__ bucket,
        const int* __restrict__ ovf_cnt, const int4* __restrict__ ovf,
        float* __restrict__ out) {
    __shared__ float row[HALF];        // 16 KB
    __shared__ float red[4];
    int b = blockIdx.x;
    int r = b >> 1;
    int base = (b & 1) << 12;          // 0 or 4096
    int t = threadIdx.x;

    f4* row4 = (f4*)row;
    #pragma unroll
    for (int k = t; k < HALF / 4; k += 256) {
        f4 z = {0.f, 0.f, 0.f, 0.f};
        row4[k] = z;
    }
    int n = cnt[r * CSTR];
    int nb = n < CAP ? n : CAP;
    __syncthreads();

    float part = 0.0f;
    for (int k = t; k < nb; k += 256) {
        Pair p = bucket[r * CAP + k];
        part += p.v;                   // full row sum (both halves)
        int cl = p.c - base;
        if ((unsigned)cl < HALF) atomicAdd(&row[cl], p.v);
    }
    int no = *ovf_cnt;
    if (no > 0) {                      // cold path, normally 0 entries
        for (int k = t; k < no; k += 256) {
            int4 e = ovf[k];
            if (e.x == r) {
                float v = __int_as_float(e.z);
                part += v;
                int cl = e.y - base;
                if ((unsigned)cl < HALF) atomicAdd(&row[cl], v);
            }
        }
    }

    #pragma unroll
    for (int o = 32; o > 0; o >>= 1) part += __shfl_down(part, o, 64);
    if ((t & 63) == 0) red[t >> 6] = part;
    __syncthreads();                   // also fences the LDS scatter atomics
    float total = red[0] + red[1] + red[2] + red[3];
    float inv = (total == 0.0f) ? 1.0f : 1.0f / total;

    f4* out4 = (f4*)(out + (size_t)r * NN + base);
    #pragma unroll
    for (int k = t; k < HALF / 4; k += 256) {
        f4 x = row4[k];
        x *= inv;
        __builtin_nontemporal_store(x, &out4[k]);
    }
}

extern "C" void kernel_launch(void* const* d_in, const int* in_sizes, int n_in,
                              void* d_out, int out_size, void* d_ws, size_t ws_size,
                              hipStream_t stream) {
    const int*   rows_s = (const int*)  d_in[0];
    const int*   cols_s = (const int*)  d_in[1];
    const float* vals_s = (const float*)d_in[2];
    const int*   rows_t = (const int*)  d_in[3];
    const int*   cols_t = (const int*)  d_in[4];
    const float* vals_t = (const float*)d_in[5];
    const float* gamma  = (const float*)d_in[6];

    float* out     = (float*)d_out;
    char*  ws      = (char*)d_ws;
    int*   cnt     = (int*)ws;                    // [NN*CSTR], padded
    int*   ovf_cnt = (int*)(ws + CNT_BYTES);      // [1]
    Pair*  bucket  = (Pair*)(ws + BK_OFF);        // [NN*CAP]
    int4*  ovf     = (int4*)(ws + OV_OFF);        // [8192]

    // Zero padded cursors + overflow counter (ws is poisoned with 0xAA).
    (void)hipMemsetAsync(ws, 0, CNT_BYTES + 4, stream);

    fill_kernel<<<TOTAL / 256, 256, 0, stream>>>(rows_s, cols_s, vals_s,
                                                 rows_t, cols_t, vals_t,
                                                 gamma, cnt, bucket, ovf_cnt, ovf);
    row_kernel<<<2 * NN, 256, 0, stream>>>(cnt, bucket, ovf_cnt, ovf, out);
}